// Round 14
// baseline (323.268 us; speedup 1.0000x reference)
//
#include <hip/hip_runtime.h>
#include <stdint.h>

#define SQL 2048
#define HID 4096
#define NHEADS 32
#define HDSZ 128
#define QKVD 4608
#define QDIM 4096

typedef unsigned short u16;
typedef __attribute__((ext_vector_type(8))) short short8;
typedef __attribute__((ext_vector_type(4))) float f32x4;

#define AS1(p) ((__attribute__((address_space(1))) void*)(p))
#define AS3(p) ((__attribute__((address_space(3))) void*)(p))

__device__ __forceinline__ float bf2f(u16 u) {
  return __uint_as_float(((uint32_t)u) << 16);
}
__device__ __forceinline__ u16 f2bf(float f) {
  uint32_t x = __float_as_uint(f);
  x += 0x7fffu + ((x >> 16) & 1u);
  return (u16)(x >> 16);
}

// ---------- fp32 -> bf16 convert, 8 elems/thread ----------
__global__ void k_cvt(const float* __restrict__ in, u16* __restrict__ out, int n8) {
  int i = blockIdx.x * blockDim.x + threadIdx.x;
  int stride = gridDim.x * blockDim.x;
  for (; i < n8; i += stride) {
    const float4* p = reinterpret_cast<const float4*>(in) + (size_t)i * 2;
    float4 a = p[0], b = p[1];
    short8 o;
    o[0] = (short)f2bf(a.x); o[1] = (short)f2bf(a.y);
    o[2] = (short)f2bf(a.z); o[3] = (short)f2bf(a.w);
    o[4] = (short)f2bf(b.x); o[5] = (short)f2bf(b.y);
    o[6] = (short)f2bf(b.z); o[7] = (short)f2bf(b.w);
    reinterpret_cast<short8*>(out)[i] = o;
  }
}

// ---------- GEMM1 (MODE 0 path): R11-verified 128x128 single-buffered ----------
__global__ __launch_bounds__(256, 2)
void k_gemm1(const u16* __restrict__ A, const u16* __restrict__ B,
             const float* __restrict__ bias,
             u16* __restrict__ qbuf, u16* __restrict__ kbuf, u16* __restrict__ vtbuf)
{
  __shared__ __align__(16) u16 ldsA[128 * 64];
  __shared__ __align__(16) u16 ldsB[128 * 64];
  const int tid = threadIdx.x;
  const int wid = tid >> 6, lane = tid & 63;
  const int l15 = lane & 15, lg = lane >> 4;
  const int m0 = blockIdx.y * 128, n0 = blockIdx.x * 128;
  const int wr = wid >> 1, wc = wid & 1;

  f32x4 acc[4][4] = {};

  const int srow = lane >> 3;
  const int skb  = (((lane & 7) ^ srow) << 4);
  const size_t rowbytes = (size_t)HID * 2;

  for (int t = 0; t < HID / 64; ++t) {
    __syncthreads();
    const char* Ab = (const char*)A + (size_t)m0 * rowbytes + (size_t)t * 128;
    const char* Bb = (const char*)B + (size_t)n0 * rowbytes + (size_t)t * 128;
#pragma unroll
    for (int i = 0; i < 4; ++i) {
      int seg = i * 4 + wid;
      int row = seg * 8 + srow;
      __builtin_amdgcn_global_load_lds(AS1(Ab + (size_t)row * rowbytes + skb),
                                       AS3(ldsA + seg * 512), 16, 0, 0);
      __builtin_amdgcn_global_load_lds(AS1(Bb + (size_t)row * rowbytes + skb),
                                       AS3(ldsB + seg * 512), 16, 0, 0);
    }
    __syncthreads();
#pragma unroll
    for (int kc = 0; kc < 2; ++kc) {
      short8 af[4], bfr[4];
#pragma unroll
      for (int mi = 0; mi < 4; ++mi) {
        int row = wr * 64 + mi * 16 + l15;
        int kb = (kc * 64 + lg * 16) ^ ((row & 7) << 4);
        af[mi] = *reinterpret_cast<const short8*>((const char*)ldsA + row * 128 + kb);
      }
#pragma unroll
      for (int ni = 0; ni < 4; ++ni) {
        int row = wc * 64 + ni * 16 + l15;
        int kb = (kc * 64 + lg * 16) ^ ((row & 7) << 4);
        bfr[ni] = *reinterpret_cast<const short8*>((const char*)ldsB + row * 128 + kb);
      }
#pragma unroll
      for (int mi = 0; mi < 4; ++mi)
#pragma unroll
        for (int ni = 0; ni < 4; ++ni)
          acc[mi][ni] = __builtin_amdgcn_mfma_f32_16x16x32_bf16(af[mi], bfr[ni], acc[mi][ni], 0, 0, 0);
    }
  }

#pragma unroll
  for (int mi = 0; mi < 4; ++mi) {
#pragma unroll
    for (int ni = 0; ni < 4; ++ni) {
      int row0 = m0 + wr * 64 + mi * 16 + lg * 4;
      int col  = n0 + wc * 64 + ni * 16 + l15;
      float bv = bias[col];
#pragma unroll
      for (int j = 0; j < 4; ++j) {
        float v = acc[mi][ni][j] + bv;
        int r = row0 + j;
        if (col < QDIM) {
          v *= 0.08838834764831845f;       // fold 1/sqrt(128) into q
          int hh = col >> 7, d = col & 127;
          qbuf[((size_t)hh * SQL + r) * HDSZ + d] = f2bf(v);
        } else if (col < QDIM + 256) {
          int c2 = col - QDIM; int g = c2 >> 7, d = c2 & 127;
          kbuf[((size_t)g * SQL + r) * HDSZ + d] = f2bf(v);
        } else {
          int c2 = col - QDIM - 256; int g = c2 >> 7, d = c2 & 127;
          vtbuf[((size_t)g * HDSZ + d) * SQL + r] = f2bf(v);   // V transposed
        }
      }
    }
  }
}

// ---------- GEMM2: deep-pipelined 128x256, 8 waves, 3-buffer LDS ----------
// Tile BM=128 x BN=256, BK=64; grid 16x16 = 256 blocks = 1/CU.
// LDS: 3 buffers of (A 16KB + B 32KB) = 144KB. tile t -> buf[t%3]; tile t+2
// staged into buf[(t+2)%3] (freed at iter t-1's closing barrier) -> no
// in-place hazards. ONE counted s_waitcnt vmcnt(6) per K-tile (phase 4):
// tile t+2's 6 loads/wave stay in flight across the barrier and land during
// iter t+1 (T4: never drain to 0 in the loop).
// 4 sub-phases per K-tile: {ds_read frag subtile; 1 stage unit; s_barrier;
// setprio(1) 8xMFMA setprio(0); s_barrier} (T3 fine interleave + T5).
__global__ __launch_bounds__(512, 2)
void k_gemm2(const u16* __restrict__ A, const u16* __restrict__ B,
             float* __restrict__ outf)
{
  __shared__ __align__(16) u16 ldsA[3][128 * 64];   // 3 x 16KB
  __shared__ __align__(16) u16 ldsB[3][256 * 64];   // 3 x 32KB
  const int tid = threadIdx.x;
  const int wid = tid >> 6, lane = tid & 63;
  const int l15 = lane & 15, lg = lane >> 4;
  const int m0 = blockIdx.y * 128, n0 = blockIdx.x * 256;
  const int wm = wid >> 2, wn = wid & 3;            // 2 x 4 wave grid
  const int rsw = (l15 & 7) << 4;                   // read-side XOR swizzle
  const size_t rb = (size_t)HID * 2;
  const int NT = HID / 64;

  f32x4 acc[4][4] = {};                             // [mi][ni]

  // staging: A = 1024 16B-chunks (2/thread), B = 2048 (4/thread, 2 units)
#define STG_A(t, b) do {                                                        \
    _Pragma("unroll")                                                           \
    for (int u_ = 0; u_ < 2; ++u_) {                                            \
      int ch_ = tid + u_ * 512;                                                 \
      int r_ = ch_ >> 3, s_ = ch_ & 7, g_ = s_ ^ (r_ & 7);                      \
      __builtin_amdgcn_global_load_lds(                                         \
        AS1((const char*)A + (size_t)(m0 + r_) * rb + (size_t)(t) * 128 + g_ * 16), \
        AS3((char*)ldsA[b] + ch_ * 16), 16, 0, 0);                              \
    } } while (0)
#define STG_B(t, b, u0) do {                                                    \
    _Pragma("unroll")                                                           \
    for (int u_ = (u0); u_ < (u0) + 2; ++u_) {                                  \
      int ch_ = tid + u_ * 512;                                                 \
      int r_ = ch_ >> 3, s_ = ch_ & 7, g_ = s_ ^ (r_ & 7);                      \
      __builtin_amdgcn_global_load_lds(                                         \
        AS1((const char*)B + (size_t)(n0 + r_) * rb + (size_t)(t) * 128 + g_ * 16), \
        AS3((char*)ldsB[b] + ch_ * 16), 16, 0, 0);                              \
    } } while (0)
#define LDA_(bf_, mi, kc) (*reinterpret_cast<const short8*>(                    \
    (const char*)ldsA[bf_] + (wm * 64 + (mi) * 16 + l15) * 128 +                \
    (((kc) * 64 + lg * 16) ^ rsw)))
#define LDB_(bf_, ni, kc) (*reinterpret_cast<const short8*>(                    \
    (const char*)ldsB[bf_] + (wn * 64 + (ni) * 16 + l15) * 128 +                \
    (((kc) * 64 + lg * 16) ^ rsw)))
#define MF8(mA, mB) do {                                                        \
    _Pragma("unroll")                                                           \
    for (int ni_ = 0; ni_ < 4; ++ni_) {                                         \
      acc[mA][ni_] = __builtin_amdgcn_mfma_f32_16x16x32_bf16(af0, bf[ni_], acc[mA][ni_], 0, 0, 0); \
      acc[mB][ni_] = __builtin_amdgcn_mfma_f32_16x16x32_bf16(af1, bf[ni_], acc[mB][ni_], 0, 0, 0); \
    } } while (0)

  // prologue: stage tiles 0 and 1; wait tile 0 (6 newest = tile 1 in flight)
  STG_A(0, 0); STG_B(0, 0, 0); STG_B(0, 0, 2);
  STG_A(1, 1); STG_B(1, 1, 0); STG_B(1, 1, 2);
  asm volatile("s_waitcnt vmcnt(6)" ::: "memory");
  __builtin_amdgcn_s_barrier();

  for (int t = 0; t < NT; ++t) {
    const int cur = t % 3, nb = (t + 2) % 3;
    const bool st = (t + 2) < NT;
    short8 af0, af1, bf[4];

    // P0: kc0 reads (A m0,m1 + B n0..3); stage A(t+2)
    af0 = LDA_(cur, 0, 0); af1 = LDA_(cur, 1, 0);
    bf[0] = LDB_(cur, 0, 0); bf[1] = LDB_(cur, 1, 0);
    bf[2] = LDB_(cur, 2, 0); bf[3] = LDB_(cur, 3, 0);
    if (st) STG_A(t + 2, nb);
    __builtin_amdgcn_s_barrier();
    __builtin_amdgcn_sched_barrier(0);
    __builtin_amdgcn_s_setprio(1);
    MF8(0, 1);
    __builtin_amdgcn_s_setprio(0);
    __builtin_amdgcn_s_barrier();

    // P1: A m2,m3 kc0; stage B(t+2) rows 0-127
    af0 = LDA_(cur, 2, 0); af1 = LDA_(cur, 3, 0);
    if (st) STG_B(t + 2, nb, 0);
    __builtin_amdgcn_s_barrier();
    __builtin_amdgcn_sched_barrier(0);
    __builtin_amdgcn_s_setprio(1);
    MF8(2, 3);
    __builtin_amdgcn_s_setprio(0);
    __builtin_amdgcn_s_barrier();

    // P2: kc1 reads; stage B(t+2) rows 128-255
    af0 = LDA_(cur, 0, 1); af1 = LDA_(cur, 1, 1);
    bf[0] = LDB_(cur, 0, 1); bf[1] = LDB_(cur, 1, 1);
    bf[2] = LDB_(cur, 2, 1); bf[3] = LDB_(cur, 3, 1);
    if (st) STG_B(t + 2, nb, 2);
    __builtin_amdgcn_s_barrier();
    __builtin_amdgcn_sched_barrier(0);
    __builtin_amdgcn_s_setprio(1);
    MF8(0, 1);
    __builtin_amdgcn_s_setprio(0);
    __builtin_amdgcn_s_barrier();

    // P3: A m2,m3 kc1; counted vmcnt (tile t+1 landed; t+2 stays in flight)
    af0 = LDA_(cur, 2, 1); af1 = LDA_(cur, 3, 1);
    __builtin_amdgcn_s_barrier();
    __builtin_amdgcn_sched_barrier(0);
    __builtin_amdgcn_s_setprio(1);
    MF8(2, 3);
    __builtin_amdgcn_s_setprio(0);
    if (st) asm volatile("s_waitcnt vmcnt(6)" ::: "memory");
    else    asm volatile("s_waitcnt vmcnt(0)" ::: "memory");
    __builtin_amdgcn_s_barrier();
  }
#undef STG_A
#undef STG_B
#undef LDA_
#undef LDB_
#undef MF8

#pragma unroll
  for (int mi = 0; mi < 4; ++mi) {
#pragma unroll
    for (int ni = 0; ni < 4; ++ni) {
      int row0 = m0 + wm * 64 + mi * 16 + lg * 4;
      int col  = n0 + wn * 64 + ni * 16 + l15;
#pragma unroll
      for (int j = 0; j < 4; ++j)
        outf[(size_t)(row0 + j) * QDIM + col] = acc[mi][ni][j];
    }
  }
}

// ---------- RoPE (interleaved pairs, first 64 dims), in place on q and k ----------
__global__ void k_rope(u16* __restrict__ qbuf, u16* __restrict__ kbuf,
                       const float* __restrict__ rope) {
  int idx = blockIdx.x * blockDim.x + threadIdx.x;
  if (idx >= SQL * 34 * 32) return;
  int p = idx & 31;
  int hh = (idx >> 5) % 34;
  int s = idx / (34 * 32);
  float c  = rope[s * 64 + p * 2 + 0];
  float sn = rope[s * 64 + p * 2 + 1];
  u16* base = (hh < 32) ? (qbuf + ((size_t)hh * SQL + s) * HDSZ)
                        : (kbuf + ((size_t)(hh - 32) * SQL + s) * HDSZ);
  u16* pp = base + 2 * p;
  uint32_t packed = *reinterpret_cast<uint32_t*>(pp);
  float x0 = bf2f((u16)(packed & 0xffff));
  float x1 = bf2f((u16)(packed >> 16));
  float o0 = x0 * c - x1 * sn;
  float o1 = x1 * c + x0 * sn;
  *reinterpret_cast<uint32_t*>(pp) = (uint32_t)f2bf(o0) | ((uint32_t)f2bf(o1) << 16);
}

// ---------- flash attention: 8-wave cooperative, LDS-staged K/V ----------
__global__ __launch_bounds__(512, 2)
void k_attn(const u16* __restrict__ qbuf, const u16* __restrict__ kbuf,
            const u16* __restrict__ vtbuf, u16* __restrict__ ctx)
{
  __shared__ __align__(16) u16 KL[2][64 * 128];     // 2 x 16 KB
  __shared__ __align__(16) u16 VL[2][128 * 64];     // 2 x 16 KB
  __shared__ uint32_t plw[8][32][36];               // per-wave P transpose
  const int tid = threadIdx.x;
  const int wid = tid >> 6, lane = tid & 63;
  const int l15 = lane & 15, lg = lane >> 4;
  const int h = blockIdx.x;
  const int g = h >> 4;                     // n_rep = 16
  const int bq = blockIdx.y;                // stripe 0..7
  const int q0 = wid * 256 + bq * 32;       // this wave's q-tile
  const int ext = q0 + 32;                  // causal extent (exclusive)
  const int NT = (1824 + 32 * bq + 63) >> 6;  // tiles to stage (max ext/64)

  const int cA = tid, cB = tid + 512;
  const int krA = cA >> 4, kiA = (cA & 15) ^ (krA & 7);
  const int krB = cB >> 4, kiB = (cB & 15) ^ (krB & 7);
  const int vrA = cA >> 3, viA = (cA & 7) ^ (vrA & 7);
  const int vrB = cB >> 3, viB = (cB & 7) ^ (vrB & 7);
  const char* kg = (const char*)(kbuf + (size_t)g * SQL * HDSZ);
  const char* vg = (const char*)(vtbuf + (size_t)g * HDSZ * SQL);

#define STAGE(t, b)                                                             \
  do {                                                                          \
    int j0s = (t) * 64;                                                         \
    __builtin_amdgcn_global_load_lds(AS1(kg + (size_t)(j0s + krA) * 256 + (kiA << 4)), \
                                     AS3((char*)KL[b] + cA * 16), 16, 0, 0);    \
    __builtin_amdgcn_global_load_lds(AS1(kg + (size_t)(j0s + krB) * 256 + (kiB << 4)), \
                                     AS3((char*)KL[b] + cB * 16), 16, 0, 0);    \
    __builtin_amdgcn_global_load_lds(AS1(vg + (size_t)vrA * (SQL * 2) + j0s * 2 + (viA << 4)), \
                                     AS3((char*)VL[b] + cA * 16), 16, 0, 0);    \
    __builtin_amdgcn_global_load_lds(AS1(vg + (size_t)vrB * (SQL * 2) + j0s * 2 + (viB << 4)), \
                                     AS3((char*)VL[b] + cB * 16), 16, 0, 0);    \
  } while (0)

  short8 aq[2][4];
#pragma unroll
  for (int rt = 0; rt < 2; ++rt) {
    const u16* qp = qbuf + ((size_t)h * SQL + q0 + rt * 16 + l15) * HDSZ + lg * 8;
#pragma unroll
    for (int kc = 0; kc < 4; ++kc)
      aq[rt][kc] = *reinterpret_cast<const short8*>(qp + kc * 32);
  }
  f32x4 o[2][8] = {};
  float mrow[2], lrow[2];
#pragma unroll
  for (int rt = 0; rt < 2; ++rt) { mrow[rt] = -__builtin_inff(); lrow[rt] = 0.f; }

  STAGE(0, 0);
  __syncthreads();

  for (int i = 0; i < NT; ++i) {
    const int cur = i & 1;
    if (i + 1 < NT) STAGE(i + 1, cur ^ 1);

    const int j0 = i * 64;
    if (j0 < ext) {
      const char* kb0 = (const char*)KL[cur];
      const char* vb0 = (const char*)VL[cur];
      const int swz = (l15 & 7) << 4;

      f32x4 st[2][4] = {};
#pragma unroll
      for (int kc = 0; kc < 4; ++kc) {
        short8 bk4[4];
#pragma unroll
        for (int kt = 0; kt < 4; ++kt) {
          int r = 16 * kt + l15;
          bk4[kt] = *reinterpret_cast<const short8*>(
              kb0 + r * 256 + ((kc * 64 + lg * 16) ^ swz));
        }
        __builtin_amdgcn_s_setprio(1);
#pragma unroll
        for (int rt = 0; rt < 2; ++rt)
#pragma unroll
          for (int kt = 0; kt < 4; ++kt)
            st[rt][kt] = __builtin_amdgcn_mfma_f32_16x16x32_bf16(bk4[kt], aq[rt][kc], st[rt][kt], 0, 0, 0);
        __builtin_amdgcn_s_setprio(0);
      }

      const bool domask = (j0 + 63 > q0);
#pragma unroll
      for (int rt = 0; rt < 2; ++rt) {
        const int q = q0 + rt * 16 + l15;
        float p[4][4];
#pragma unroll
        for (int kt = 0; kt < 4; ++kt)
#pragma unroll
          for (int j = 0; j < 4; ++j) {
            float v = st[rt][kt][j];
            if (domask) {
              int kvi = j0 + kt * 16 + lg * 4 + j;
              v = (kvi > q) ? -1e30f : v;
            }
            p[kt][j] = v;
          }
        float rm = fmaxf(fmaxf(fmaxf(p[0][0], p[0][1]), fmaxf(p[0][2], p[0][3])),
                         fmaxf(fmaxf(p[1][0], p[1][1]), fmaxf(p[1][2], p[1][3])));
        rm = fmaxf(rm, fmaxf(fmaxf(fmaxf(p[2][0], p[2][1]), fmaxf(p[2][2], p[2][3])),
                             fmaxf(fmaxf(p[3][0], p[3][1]), fmaxf(p[3][2], p[3][3]))));
        rm = fmaxf(rm, __shfl_xor(rm, 16));
        rm = fmaxf(rm, __shfl_xor(rm, 32));
        if (!__all(rm <= mrow[rt] + 8.0f)) {        // defer-rescale (T13)
          float mn = fmaxf(mrow[rt], rm);
          float a = __expf(mrow[rt] - mn);          // first tile: exp(-inf)=0
          mrow[rt] = mn;
          lrow[rt] *= a;
          float ar[4];
#pragma unroll
          for (int j = 0; j < 4; ++j) ar[j] = __shfl(a, lg * 4 + j);
#pragma unroll
          for (int df = 0; df < 8; ++df) {
            o[rt][df][0] *= ar[0]; o[rt][df][1] *= ar[1];
            o[rt][df][2] *= ar[2]; o[rt][df][3] *= ar[3];
          }
        }
        float ps = 0.f;
#pragma unroll
        for (int kt = 0; kt < 4; ++kt)
#pragma unroll
          for (int j = 0; j < 4; ++j) {
            p[kt][j] = __expf(p[kt][j] - mrow[rt]);
            ps += p[kt][j];
          }
        ps += __shfl_xor(ps, 16);
        ps += __shfl_xor(ps, 32);
        lrow[rt] += ps;
#pragma unroll
        for (int kt = 0; kt < 4; ++kt)
#pragma unroll
          for (int u = 0; u < 2; ++u) {
            uint32_t W;
            asm("v_cvt_pk_bf16_f32 %0, %1, %2"
                : "=v"(W) : "v"(p[kt][2 * u]), "v"(p[kt][2 * u + 1]));
            plw[wid][rt * 16 + l15][8 * kt + 2 * lg + u] = W;
          }
      }
      asm volatile("s_waitcnt lgkmcnt(0)" ::: "memory");  // wave-local write->read

      short8 ap[2][2];
#pragma unroll
      for (int rt = 0; rt < 2; ++rt)
#pragma unroll
        for (int kc2 = 0; kc2 < 2; ++kc2)
          ap[rt][kc2] = *reinterpret_cast<const short8*>(&plw[wid][rt * 16 + l15][16 * kc2 + 4 * lg]);

      __builtin_amdgcn_s_setprio(1);
#pragma unroll
      for (int df = 0; df < 8; ++df) {
        short8 bv0, bv1;
        int rv = l15 + 16 * df;
#pragma unroll
        for (int kc2 = 0; kc2 < 2; ++kc2) {
          short8 bvv = *reinterpret_cast<const short8*>(
              vb0 + rv * 128 + ((kc2 * 64 + lg * 16) ^ swz));
          if (kc2 == 0) bv0 = bvv; else bv1 = bvv;
        }
#pragma unroll
        for (int rt = 0; rt < 2; ++rt) {
          f32x4 t = o[rt][df];
          t = __builtin_amdgcn_mfma_f32_16x16x32_bf16(ap[rt][0], bv0, t, 0, 0, 0);
          t = __builtin_amdgcn_mfma_f32_16x16x32_bf16(ap[rt][1], bv1, t, 0, 0, 0);
          o[rt][df] = t;
        }
      }
      __builtin_amdgcn_s_setprio(0);
    }
    __syncthreads();
  }

#pragma unroll
  for (int rt = 0; rt < 2; ++rt) {
    float linv[4];
#pragma unroll
    for (int j = 0; j < 4; ++j) linv[j] = 1.0f / __shfl(lrow[rt], lg * 4 + j);
#pragma unroll
    for (int j = 0; j < 4; ++j) {
      int row = q0 + rt * 16 + lg * 4 + j;
      u16* cp = ctx + (size_t)row * QDIM + h * HDSZ;
#pragma unroll
      for (int df = 0; df < 8; ++df)
        cp[df * 16 + l15] = f2bf(o[rt][df][j] * linv[j]);
    }
  }
#undef STAGE
}

// ---------- workspace layout (bytes) ----------
//  0        : hidden_bf16 [2048][4096]   16777216   (reused as ctx after GEMM1)
//  16777216 : W_bf16      [4608][4096]   37748736   (Wqkv, then Wdense)
//  54525952 : q           [32][2048][128] 16777216
//  71303168 : k           [2][2048][128]   1048576
//  72351744 : vt          [2][128][2048]   1048576
//  total 73400320

extern "C" void kernel_launch(void* const* d_in, const int* in_sizes, int n_in,
                              void* d_out, int out_size, void* d_ws, size_t ws_size,
                              hipStream_t stream) {
  const float* hs     = (const float*)d_in[0];
  const float* wqkv   = (const float*)d_in[1];
  const float* bqkv   = (const float*)d_in[2];
  const float* wdense = (const float*)d_in[3];
  const float* rope   = (const float*)d_in[4];
  char* ws = (char*)d_ws;
  u16* hid_b = (u16*)(ws + 0);
  u16* w_b   = (u16*)(ws + 16777216);
  u16* qb    = (u16*)(ws + 54525952);
  u16* kb    = (u16*)(ws + 71303168);
  u16* vtb   = (u16*)(ws + 72351744);
  u16* ctx   = hid_b;                      // reuse after GEMM1
  float* outf = (float*)d_out;

  k_cvt<<<2048, 256, 0, stream>>>(hs,   hid_b, SQL * HID / 8);
  k_cvt<<<2048, 256, 0, stream>>>(wqkv, w_b,   QKVD * HID / 8);
  k_gemm1<<<dim3(QKVD / 128, SQL / 128), 256, 0, stream>>>(
      hid_b, w_b, bqkv, qb, kb, vtb);
  k_rope<<<(SQL * 34 * 32) / 256, 256, 0, stream>>>(qb, kb, rope);
  k_cvt<<<2048, 256, 0, stream>>>(wdense, w_b, QDIM * HID / 8);   // after GEMM1
  k_attn<<<dim3(NHEADS, 8), 512, 0, stream>>>(qb, kb, vtb, ctx);
  k_gemm2<<<dim3(QDIM / 256, SQL / 128), 512, 0, stream>>>(ctx, w_b, outf);
}